// Round 14
// baseline (33.284 us; speedup 1.0000x reference)
//
#include <hip/hip_runtime.h>
#include <hip/hip_bf16.h>

typedef __attribute__((ext_vector_type(4))) float f32x4;
typedef __attribute__((ext_vector_type(8))) __bf16 bf16x8;
typedef __attribute__((ext_vector_type(4))) __bf16 bf16x4;

#define B_DIM 16
#define L_DIM 1024
#define D_DIM 256

#define GLOAD_LDS16(g, lptr)                                          \
    __builtin_amdgcn_global_load_lds(                                 \
        (const __attribute__((address_space(1))) void*)(g),           \
        (__attribute__((address_space(3))) void*)(lptr), 16, 0, 0)

#define SBAR() __builtin_amdgcn_sched_barrier(0)

// ---------------------------------------------------------------------------
// Prep: row norms + fp32->bf16 conversion in one pass (r4/r9-proven).
// ---------------------------------------------------------------------------
__global__ __launch_bounds__(256) void prep_kernel(const float* __restrict__ s1,
                                                   const float* __restrict__ s2,
                                                   float* __restrict__ nrm,
                                                   __hip_bfloat16* __restrict__ s1b,
                                                   __hip_bfloat16* __restrict__ s2b) {
    const int w = threadIdx.x >> 6, l = threadIdx.x & 63;
    const int base = (blockIdx.x << 4) + (w << 2);  // 16 rows/block, 4/wave
#pragma unroll
    for (int i = 0; i < 4; ++i) {
        const int row = base + i;          // 0 .. 32767
        const int second = row >> 14;      // rows >= 16384 are s2 (wave-uniform)
        const int r = row & 16383;
        const float* src = (second ? s2 : s1) + (size_t)r * D_DIM;
        __hip_bfloat16* dst = (second ? s2b : s1b) + (size_t)r * D_DIM;
        float4 v = reinterpret_cast<const float4*>(src)[l];
        float s = v.x * v.x + v.y * v.y + v.z * v.z + v.w * v.w;
        bf16x4 bv;
        bv[0] = (__bf16)v.x; bv[1] = (__bf16)v.y; bv[2] = (__bf16)v.z; bv[3] = (__bf16)v.w;
        *reinterpret_cast<bf16x4*>(dst + l * 4) = bv;
#pragma unroll
        for (int o = 32; o > 0; o >>= 1) s += __shfl_xor(s, o, 64);
        if (l == 0) nrm[row] = s;
    }
}

// ---------------------------------------------------------------------------
// 4-tile A-resident GEMM. Grid 256 (1 block/CU), 512 threads (8 waves, 2x4
// wave grid per tile). Block owns 128-row panel x 512 cols = 4 col-tiles.
//  - Afull[8][128x32]: whole A panel (all K) staged ONCE during tile 0.
//  - Blds[4][128x32]: B streams through 4 bufs (r13-proven schedule).
//  - Tiles 1-3 stage only B (1 op/wave/stage); 3 of 4 epilogue store bursts
//    overlap the next tile's K-loop.
// Waits (derived, in-order retire):
//  tile0 (2-op A+B stages): prestage(0-3)=8op; vmcnt(0); loop stages kt=1..4;
//    vmcnt(2)@kt3-5 (leaves stage(kt+2) pair), vmcnt(0)@kt6.
//  tiles1-3 (1-op B stages): transition prestage B0-3=4op; vmcnt(3) (B0
//    landed, B1-3 in flight); loop stageB(kt+3) kt=1..4; vmcnt(1)@kt3-5
//    (leaves stage(kt+2); drains the 32 epilogue stores at kt=3, ~4 steps
//    after issue), vmcnt(0)@kt6.
//  lgkmcnt(6) drains frags(kt) (6 ds_read/set), keeps frags(kt+1) flying.
// Race-safety: barrier at transition top AFTER kt=7's lgkmcnt(0) so no
// wave's frags(7) ds_reads are outstanding when Blds is re-staged; per-step
// barrier + lgkm induction identical to r13 for all other overwrites.
// ---------------------------------------------------------------------------
__global__ __launch_bounds__(512, 2) void dist_gemm4_kernel(const __hip_bfloat16* __restrict__ s1b,
                                                            const __hip_bfloat16* __restrict__ s2b,
                                                            const float* __restrict__ nrm,
                                                            float* __restrict__ out) {
    __shared__ __bf16 Afull[8][128 * 32];   // 64 KB: whole A panel
    __shared__ __bf16 Blds[4][128 * 32];    // 32 KB: B ring

    const int t = threadIdx.x;
    const int p = blockIdx.x;
    // XCD swizzle (256 blocks): XCD x owns d in [32x,32x+32) = 2 batches.
    const int d = ((p & 7) << 5) + (p >> 3);
    const int batch = d >> 4;
    const int rem = d & 15;                 // 8 row-panels x 2 col-halves
    const int row0 = (rem >> 1) << 7;
    const int colq = (rem & 1) << 9;        // 0 or 512

    const __hip_bfloat16* Ag = s1b + ((size_t)batch * L_DIM + row0) * D_DIM;
    const __hip_bfloat16* Bgq = s2b + ((size_t)batch * L_DIM + colq) * D_DIM;

    const int l = t & 63, w = t >> 6;       // 8 waves
    const int wr = w >> 2, wc = w & 3;      // wave -> 64x32 output quadrant
    const int lr = l & 15;                  // frag row (A) / col (B,C)
    const int lq = l >> 4;                  // 16B k-slot

    const int srow = l >> 2;                // staging: wave w = seg w (16 rows)
    const int sslot = (l & 3) ^ ((l >> 3) & 3);

    auto stageA = [&](int kt) {             // 1 gload_lds
        const int rl = (w << 4) + srow;
        GLOAD_LDS16(Ag + rl * D_DIM + (kt << 5) + sslot * 8, &Afull[kt][w << 9]);
    };
    auto stageB = [&](const __hip_bfloat16* Bg, int kt) {  // 1 gload_lds
        const int rl = (w << 4) + srow;
        GLOAD_LDS16(Bg + rl * D_DIM + (kt << 5) + sslot * 8, &Blds[kt & 3][w << 9]);
    };

    bf16x8 aF[2][4], bF[2][2];
    auto readFrags = [&](int kt, bf16x8* a, bf16x8* bfr) {  // 6 ds_read_b128
#pragma unroll
        for (int m = 0; m < 4; ++m) {
            const int row = (wr << 6) + (m << 4) + lr;
            const int sl = lq ^ ((row >> 1) & 3);
            a[m] = *reinterpret_cast<const bf16x8*>(&Afull[kt][(row << 5) + (sl << 3)]);
        }
#pragma unroll
        for (int n = 0; n < 2; ++n) {
            const int row = (wc << 5) + (n << 4) + lr;
            const int sl = lq ^ ((row >> 1) & 3);
            bfr[n] = *reinterpret_cast<const bf16x8*>(&Blds[kt & 3][(row << 5) + (sl << 3)]);
        }
    };

    const float* x2 = nrm + batch * L_DIM;
    const float* y2 = nrm + B_DIM * L_DIM + batch * L_DIM;
    const int rbase = row0 + (wr << 6) + (lq << 2);
    const int cloc = (wc << 5) + lr;
    float* outb = out + (size_t)batch * L_DIM * L_DIM;

    f32x4 acc[4][2];
    auto zeroAcc = [&]() {
#pragma unroll
        for (int m = 0; m < 4; ++m)
#pragma unroll
            for (int n = 0; n < 2; ++n) acc[m][n] = f32x4{0.f, 0.f, 0.f, 0.f};
    };

    auto epilogue = [&](const f32x4 (&xv)[4], const float* yv, int colb) {
#pragma unroll
        for (int n = 0; n < 2; ++n) {
            const int col = colb + cloc + (n << 4);
            const float y2v = yv[n];
#pragma unroll
            for (int m = 0; m < 4; ++m) {
#pragma unroll
                for (int r = 0; r < 4; ++r) {
                    const int row = rbase + (m << 4) + r;
                    float sq = fmaxf(xv[m][r] + y2v - 2.0f * acc[m][n][r], 0.0f);
                    outb[(size_t)row * L_DIM + col] =
                        __builtin_amdgcn_rcpf(1.0f + __builtin_amdgcn_sqrtf(sq));
                }
            }
        }
    };

    // ===================== PROLOGUE ========================================
    f32x4 xv[4]; float yv4[4][2];
#pragma unroll
    for (int m = 0; m < 4; ++m) xv[m] = *reinterpret_cast<const f32x4*>(&x2[rbase + (m << 4)]);
#pragma unroll
    for (int tau = 0; tau < 4; ++tau)
#pragma unroll
        for (int n = 0; n < 2; ++n) yv4[tau][n] = y2[colq + (tau << 7) + cloc + (n << 4)];
    SBAR();
    zeroAcc();
#pragma unroll
    for (int kt = 0; kt < 4; ++kt) { stageA(kt); stageB(Bgq, kt); }
    SBAR();
    asm volatile("s_waitcnt vmcnt(0)" ::: "memory");
    __builtin_amdgcn_s_barrier();
    readFrags(0, aF[0], bF[0]);

    // ===================== TILE 0 K-LOOP (stages A+B) ======================
#pragma unroll
    for (int kt = 0; kt < 8; ++kt) {
        if (kt >= 3 && kt <= 5) asm volatile("s_waitcnt vmcnt(2)" ::: "memory");
        else if (kt == 6)       asm volatile("s_waitcnt vmcnt(0)" ::: "memory");
        if (kt >= 1) __builtin_amdgcn_s_barrier();
        if (kt < 7) readFrags(kt + 1, aF[(kt + 1) & 1], bF[(kt + 1) & 1]);
        if (kt < 7) asm volatile("s_waitcnt lgkmcnt(6)" ::: "memory");
        else        asm volatile("s_waitcnt lgkmcnt(0)" ::: "memory");
        if (kt >= 1 && kt <= 4) { stageA(kt + 3); stageB(Bgq, kt + 3); }
        __builtin_amdgcn_s_setprio(1);
#pragma unroll
        for (int m = 0; m < 4; ++m)
#pragma unroll
            for (int n = 0; n < 2; ++n)
                acc[m][n] = __builtin_amdgcn_mfma_f32_16x16x32_bf16(
                    aF[kt & 1][m], bF[kt & 1][n], acc[m][n], 0, 0, 0);
        __builtin_amdgcn_s_setprio(0);
    }

    // ===================== TILES 1..3 ======================================
#pragma unroll
    for (int tau = 1; tau < 4; ++tau) {
        const __hip_bfloat16* Bg = Bgq + (size_t)(tau << 7) * D_DIM;
        // safety barrier: all waves past kt=7's lgkmcnt(0) (frags(7) drained)
        __builtin_amdgcn_s_barrier();
#pragma unroll
        for (int kt = 0; kt < 4; ++kt) stageB(Bg, kt);
        SBAR();
        asm volatile("s_waitcnt vmcnt(3)" ::: "memory");   // B0 landed
        __builtin_amdgcn_s_barrier();
        readFrags(0, aF[0], bF[0]);        // ds_reads overlap epilogue VALU
        epilogue(xv, yv4[tau - 1], colq + ((tau - 1) << 7));  // 32 stores, fire&forget
        SBAR();
        zeroAcc();

#pragma unroll
        for (int kt = 0; kt < 8; ++kt) {
            if (kt >= 3 && kt <= 5) asm volatile("s_waitcnt vmcnt(1)" ::: "memory");
            else if (kt == 6)       asm volatile("s_waitcnt vmcnt(0)" ::: "memory");
            if (kt >= 1) __builtin_amdgcn_s_barrier();
            if (kt < 7) readFrags(kt + 1, aF[(kt + 1) & 1], bF[(kt + 1) & 1]);
            if (kt < 7) asm volatile("s_waitcnt lgkmcnt(6)" ::: "memory");
            else        asm volatile("s_waitcnt lgkmcnt(0)" ::: "memory");
            if (kt >= 1 && kt <= 4) stageB(Bg, kt + 3);
            __builtin_amdgcn_s_setprio(1);
#pragma unroll
            for (int m = 0; m < 4; ++m)
#pragma unroll
                for (int n = 0; n < 2; ++n)
                    acc[m][n] = __builtin_amdgcn_mfma_f32_16x16x32_bf16(
                        aF[kt & 1][m], bF[kt & 1][n], acc[m][n], 0, 0, 0);
            __builtin_amdgcn_s_setprio(0);
        }
    }

    epilogue(xv, yv4[3], colq + 384);   // terminal
}

// ---------------------------------------------------------------------------
// Fallback path for the case ws_size < needed.
// ---------------------------------------------------------------------------
__global__ __launch_bounds__(256) void norms_kernel(const float* __restrict__ s1,
                                                    const float* __restrict__ s2,
                                                    float* __restrict__ nrm) {
    int w = threadIdx.x >> 6, l = threadIdx.x & 63;
    int row = (blockIdx.x << 2) + w;
    const float* src = (row < B_DIM * L_DIM)
                           ? (s1 + (size_t)row * D_DIM)
                           : (s2 + (size_t)(row - B_DIM * L_DIM) * D_DIM);
    float4 v = reinterpret_cast<const float4*>(src)[l];
    float s = v.x * v.x + v.y * v.y + v.z * v.z + v.w * v.w;
#pragma unroll
    for (int o = 32; o > 0; o >>= 1) s += __shfl_xor(s, o, 64);
    if (l == 0) nrm[row] = s;
}

__global__ __launch_bounds__(256) void dist_gemm_kernel(const float* __restrict__ s1,
                                                        const float* __restrict__ s2,
                                                        const float* __restrict__ nrm,
                                                        float* __restrict__ out) {
    __shared__ __bf16 Alds[2][128 * 32];
    __shared__ __bf16 Blds2[2][128 * 32];

    const int t = threadIdx.x;
    const int p = blockIdx.x;
    const int d = ((p & 7) << 7) + (p >> 3);
    const int batch = d >> 6;
    const int tile = d & 63;
    const int row0 = (tile >> 3) << 7;
    const int col0 = (tile & 7) << 7;

    const float* Ag = s1 + ((size_t)batch * L_DIM + row0) * D_DIM;
    const float* Bg = s2 + ((size_t)batch * L_DIM + col0) * D_DIM;

    const int sr = t >> 2;
    const int sc = (t & 3) << 3;

    const int l = t & 63, w = t >> 6;
    const int wr = w >> 1, wc = w & 1;
    const int lr = l & 15;
    const int lk = (l >> 4) << 3;

    f32x4 acc[4][4] = {};

    auto stage = [&](int buf, int k0) {
#pragma unroll
        for (int pass = 0; pass < 2; ++pass) {
            const int r = sr + (pass << 6);
            const float4* sa = reinterpret_cast<const float4*>(Ag + (size_t)r * D_DIM + k0 + sc);
            float4 a0 = sa[0], a1 = sa[1];
            const float4* sb = reinterpret_cast<const float4*>(Bg + (size_t)r * D_DIM + k0 + sc);
            float4 b0 = sb[0], b1 = sb[1];
            bf16x8 av, bv;
            av[0] = (__bf16)a0.x; av[1] = (__bf16)a0.y; av[2] = (__bf16)a0.z; av[3] = (__bf16)a0.w;
            av[4] = (__bf16)a1.x; av[5] = (__bf16)a1.y; av[6] = (__bf16)a1.z; av[7] = (__bf16)a1.w;
            bv[0] = (__bf16)b0.x; bv[1] = (__bf16)b0.y; bv[2] = (__bf16)b0.z; bv[3] = (__bf16)b0.w;
            bv[4] = (__bf16)b1.x; bv[5] = (__bf16)b1.y; bv[6] = (__bf16)b1.z; bv[7] = (__bf16)b1.w;
            *reinterpret_cast<bf16x8*>(&Alds[buf][(r << 5) + sc]) = av;
            *reinterpret_cast<bf16x8*>(&Blds2[buf][(r << 5) + sc]) = bv;
        }
    };

    stage(0, 0);
    __syncthreads();
    int cur = 0;
    for (int kt = 0; kt < 8; ++kt) {
        if (kt < 7) stage(cur ^ 1, (kt + 1) << 5);
        bf16x8 aF[4], bF[4];
#pragma unroll
        for (int m = 0; m < 4; ++m)
            aF[m] = *reinterpret_cast<const bf16x8*>(
                &Alds[cur][(((wr << 6) + (m << 4) + lr) << 5) + lk]);
#pragma unroll
        for (int n = 0; n < 4; ++n)
            bF[n] = *reinterpret_cast<const bf16x8*>(
                &Blds2[cur][(((wc << 6) + (n << 4) + lr) << 5) + lk]);
#pragma unroll
        for (int m = 0; m < 4; ++m)
#pragma unroll
            for (int n = 0; n < 4; ++n)
                acc[m][n] = __builtin_amdgcn_mfma_f32_16x16x32_bf16(aF[m], bF[n], acc[m][n], 0, 0, 0);
        __syncthreads();
        cur ^= 1;
    }

    const float* x2 = nrm + batch * L_DIM;
    const float* y2 = nrm + B_DIM * L_DIM + batch * L_DIM;
    float* outb = out + (size_t)batch * L_DIM * L_DIM;
    const int rbase = row0 + (wr << 6) + ((l >> 4) << 2);
    const int cbase = col0 + (wc << 6) + lr;
#pragma unroll
    for (int n = 0; n < 4; ++n) {
        const int col = cbase + (n << 4);
        const float y2v = y2[col];
#pragma unroll
        for (int m = 0; m < 4; ++m) {
            const int rowf = rbase + (m << 4);
#pragma unroll
            for (int r = 0; r < 4; ++r) {
                const int row = rowf + r;
                float sq = x2[row] + y2v - 2.0f * acc[m][n][r];
                sq = fmaxf(sq, 0.0f);
                outb[(size_t)row * L_DIM + col] = 1.0f / (1.0f + sqrtf(sq));
            }
        }
    }
}

extern "C" void kernel_launch(void* const* d_in, const int* in_sizes, int n_in,
                              void* d_out, int out_size, void* d_ws, size_t ws_size,
                              hipStream_t stream) {
    (void)in_sizes; (void)n_in; (void)out_size;
    const float* s1 = (const float*)d_in[1];
    const float* s2 = (const float*)d_in[2];
    float* out = (float*)d_out;

    const size_t NRM_BYTES = 2u * B_DIM * L_DIM * sizeof(float);          // 128 KB
    const size_t BF_BYTES = (size_t)B_DIM * L_DIM * D_DIM * sizeof(__hip_bfloat16);  // 8 MB each
    const size_t NEED = NRM_BYTES + 2 * BF_BYTES;                          // ~16.9 MB

    float* nrm = (float*)d_ws;
    if (ws_size >= NEED) {
        __hip_bfloat16* s1b = (__hip_bfloat16*)((char*)d_ws + NRM_BYTES);
        __hip_bfloat16* s2b = (__hip_bfloat16*)((char*)d_ws + NRM_BYTES + BF_BYTES);
        prep_kernel<<<2048, 256, 0, stream>>>(s1, s2, nrm, s1b, s2b);
        dist_gemm4_kernel<<<256, 512, 0, stream>>>(s1b, s2b, nrm, out);
    } else {
        norms_kernel<<<8192, 256, 0, stream>>>(s1, s2, nrm);
        dist_gemm_kernel<<<1024, 256, 0, stream>>>(s1, s2, nrm, out);
    }
}